// Round 2
// baseline (84.800 us; speedup 1.0000x reference)
//
#include <hip/hip_runtime.h>
#include <hip/hip_bf16.h>
#include <stdint.h>

#define BATCH 256
#define INF   1024
#define OUTF  128
#define KD    8
#define NN    1024   // OUTF*KD
#define OROW  1152   // INF + OUTF
#define BLP   1032   // Bl row pad: (rc*516)%32 spreads banks; 2064 B row stride keeps 16-B align
#define MOP   10     // Mo row pad: 40 B rows -> zero-conflict epilogue, float2-aligned

typedef __attribute__((ext_vector_type(8))) short short8;
typedef __attribute__((ext_vector_type(4))) float f32x4;

__device__ __forceinline__ unsigned short f2bf(float f) {
    union { float f; uint32_t u; } v; v.f = f;
    uint32_t r = v.u + 0x7FFFu + ((v.u >> 16) & 1u);   // RNE
    return (unsigned short)(r >> 16);
}
__device__ __forceinline__ uint32_t pack2(float lo, float hi) {
    return (uint32_t)f2bf(lo) | ((uint32_t)f2bf(hi) << 16);
}

// K1: x fp32 -> xbf (bf16) + exact fp32 copy of x into out[:, 0:1024].
// 128 blocks x 256 thr, 8 floats/thread, fully coalesced.
__global__ __launch_bounds__(256) void prep_kernel(
    const float* __restrict__ x, float* __restrict__ out,
    unsigned short* __restrict__ xbf)
{
    int g = (blockIdx.x * 256 + threadIdx.x) * 8;
    int a = g >> 10, j = g & 1023;
    float4 v0 = *(const float4*)(x + g);
    float4 v1 = *(const float4*)(x + g + 4);
    *(float4*)(out + (size_t)a * OROW + j)     = v0;
    *(float4*)(out + (size_t)a * OROW + j + 4) = v1;
    uint4 u;
    u.x = pack2(v0.x, v0.y);
    u.y = pack2(v0.z, v0.w);
    u.z = pack2(v1.x, v1.y);
    u.w = pack2(v1.z, v1.w);
    *(uint4*)(xbf + g) = u;
}

// K2: fused per-(o, a-half) block: stage B=T[:,o,:] in LDS (bf16, n-major),
// MFMA GEMM -> Mo (256x8 in LDS), pair L1+exp from LDS, write c column.
// 256 blocks x 512 thr (8 waves). No global M, no atomics, no c-init.
__global__ __launch_bounds__(512) void fused_kernel(
    const unsigned short* __restrict__ xbf,
    const float* __restrict__ T,
    float* __restrict__ out)
{
    __shared__ __align__(16) unsigned short Bl[8 * BLP];   // 16.1 KB
    __shared__ __align__(16) float Mo[256 * MOP];          // 10 KB
    __shared__ float lds_c[128 * 4];                       // 2 KB
    int bid = blockIdx.x;
    int o = bid >> 1, ah = bid & 1;
    int t = threadIdx.x;

    // ---- stage Bl[n][k] = bf16(T[k][o*8+n]), k-contiguous per n ----
    const float* Tb = T + o * 8;
#pragma unroll
    for (int p = 0; p < 4; ++p) {
        int f = p * 512 + t;          // 0..2047
        int i = f >> 1;               // k row 0..1023
        int h = (f & 1) * 4;          // col group 0..3 / 4..7
        float4 v = *(const float4*)(Tb + (size_t)i * NN + h);
        Bl[(h + 0) * BLP + i] = f2bf(v.x);
        Bl[(h + 1) * BLP + i] = f2bf(v.y);
        Bl[(h + 2) * BLP + i] = f2bf(v.z);
        Bl[(h + 3) * BLP + i] = f2bf(v.w);
    }
    __syncthreads();

    // ---- GEMM: wave w computes Mo rows [w*32, w*32+32), full K=1024 ----
    int w = t >> 6, lane = t & 63, rc = lane & 15, quad = lane >> 4;
    {
        const unsigned short* pa0 = xbf + (size_t)(w * 32 + rc) * INF + quad * 8;
        const unsigned short* pa1 = pa0 + 16 * INF;
        const unsigned short* bl = Bl + (rc & 7) * BLP + quad * 8;  // cols 8..15 duplicate 0..7, discarded
        f32x4 acc0 = {0.f, 0.f, 0.f, 0.f}, acc1 = {0.f, 0.f, 0.f, 0.f};
#pragma unroll 4
        for (int s = 0; s < 32; ++s) {
            short8 bf = *(const short8*)(bl + s * 32);
            short8 a0 = *(const short8*)(pa0 + s * 32);
            short8 a1 = *(const short8*)(pa1 + s * 32);
            acc0 = __builtin_amdgcn_mfma_f32_16x16x32_bf16(a0, bf, acc0, 0, 0, 0);
            acc1 = __builtin_amdgcn_mfma_f32_16x16x32_bf16(a1, bf, acc1, 0, 0, 0);
        }
        // C/D layout: col=lane&15, row=quad*4+r  [m89/m91]
        if (rc < 8) {
#pragma unroll
            for (int r = 0; r < 4; ++r) {
                Mo[(w * 32 + quad * 4 + r) * MOP + rc]      = acc0[r];
                Mo[(w * 32 + 16 + quad * 4 + r) * MOP + rc] = acc1[r];
            }
        }
    }
    __syncthreads();

    // ---- pair: thread (a_l, q): rows a_g = ah*128+a_l, b in quarter q ----
    int a_l = t & 127, q = t >> 7;        // q uniform per wave
    int a_g = ah * 128 + a_l;
    float2 m0 = *(const float2*)&Mo[a_g * MOP + 0];
    float2 m1 = *(const float2*)&Mo[a_g * MOP + 2];
    float2 m2 = *(const float2*)&Mo[a_g * MOP + 4];
    float2 m3 = *(const float2*)&Mo[a_g * MOP + 6];
    float ssum = 0.f;
#pragma unroll 4
    for (int it = 0; it < 64; ++it) {
        int b = q * 64 + it;              // wave-uniform -> LDS broadcast reads
        float2 q0 = *(const float2*)&Mo[b * MOP + 0];
        float2 q1 = *(const float2*)&Mo[b * MOP + 2];
        float2 q2 = *(const float2*)&Mo[b * MOP + 4];
        float2 q3 = *(const float2*)&Mo[b * MOP + 6];
        float d = fabsf(m0.x - q0.x) + fabsf(m0.y - q0.y)
                + fabsf(m1.x - q1.x) + fabsf(m1.y - q1.y)
                + fabsf(m2.x - q2.x) + fabsf(m2.y - q2.y)
                + fabsf(m3.x - q3.x) + fabsf(m3.y - q3.y);
        ssum += __expf(-d);
    }
    lds_c[a_l * 4 + q] = ssum;
    __syncthreads();
    if (t < 128) {
        float4 v = *(const float4*)&lds_c[t * 4];
        // self term exp(0)=1 included exactly once across quarters -> subtract 1
        out[(size_t)(ah * 128 + t) * OROW + INF + o] = v.x + v.y + v.z + v.w - 1.0f;
    }
}

extern "C" void kernel_launch(void* const* d_in, const int* in_sizes, int n_in,
                              void* d_out, int out_size, void* d_ws, size_t ws_size,
                              hipStream_t stream) {
    const float* x = (const float*)d_in[0];
    const float* T = (const float*)d_in[1];
    float* out = (float*)d_out;
    unsigned short* xbf = (unsigned short*)d_ws;   // 512 KB

    prep_kernel<<<128, 256, 0, stream>>>(x, out, xbf);
    fused_kernel<<<256, 512, 0, stream>>>(xbf, T, out);
}